// Round 4
// baseline (303.223 us; speedup 1.0000x reference)
//
#include <hip/hip_runtime.h>
#include <hip/hip_bf16.h>

typedef __attribute__((ext_vector_type(8))) short bf16x8;
typedef __attribute__((ext_vector_type(4))) float f32x4;

#define NQ 2500
#define NKK 6336
#define NHEADS 4
#define DHEAD 32
// SCALE * log2(e): p = exp2(s * c)
#define CSC 0.25503482f

// workspace byte offsets
#define WS_QP 0
#define WS_KP 640000
#define WS_VT 2262016
#define WS_WB 3884032
#define WS_OP 4146176
// Opart: per split 2500 rows x 136 floats (128 O + 4 l per head)
#define OSPLIT_F 340000
#define OROW_F 136
#define WS_REQ3 8226176ULL

// bf16 weight element offsets inside WS_WB
#define WQB 0
#define WKB 16384
#define WVB 32768
#define WPROJB 49152
#define W1B 65536
#define W2B 98304

#define NTILES_TOTAL 99
#define TQ 16
#define ATQ 16
#define TK 64
#define QBLOCKS 157
#define AQBLOCKS 157

__device__ __forceinline__ unsigned short bf16bits(float x) {
  union { __hip_bfloat16 h; unsigned short s; } cv;
  cv.h = __float2bfloat16(x);
  return cv.s;
}

// ============ weight fp32->bf16 conversion (once per launch) ============
__global__ __launch_bounds__(256) void wconv_kernel(
    const float* __restrict__ wq, const float* __restrict__ wk,
    const float* __restrict__ wv, const float* __restrict__ wproj,
    const float* __restrict__ w1, const float* __restrict__ w2,
    __hip_bfloat16* __restrict__ wb)
{
  int e = (blockIdx.x * 256 + threadIdx.x) * 4;
  const float* src; int off;
  if (e < 16384)      { src = wq;    off = e; }
  else if (e < 32768) { src = wk;    off = e - 16384; }
  else if (e < 49152) { src = wv;    off = e - 32768; }
  else if (e < 65536) { src = wproj; off = e - 49152; }
  else if (e < 98304) { src = w1;    off = e - 65536; }
  else                { src = w2;    off = e - 98304; }
  float4 v = *(const float4*)(src + off);
  ushort4 o4;
  o4.x = bf16bits(v.x); o4.y = bf16bits(v.y); o4.z = bf16bits(v.z); o4.w = bf16bits(v.w);
  *(ushort4*)((unsigned short*)wb + e) = o4;
}

// ============ lnproj: LN + 128x128 projection (MFMA), 32 rows/block, 256 thr ============
__global__ __launch_bounds__(256) void lnproj_kernel(
    const float* __restrict__ qin, const float* __restrict__ kin, const float* __restrict__ vin,
    const float* __restrict__ qn_g, const float* __restrict__ qn_b,
    const float* __restrict__ kn_g, const float* __restrict__ kn_b,
    const float* __restrict__ vn_g, const float* __restrict__ vn_b,
    const __hip_bfloat16* __restrict__ wball,
    const float* __restrict__ bq, const float* __restrict__ bk, const float* __restrict__ bv,
    __hip_bfloat16* __restrict__ Qp, __hip_bfloat16* __restrict__ Kp,
    __hip_bfloat16* __restrict__ Vt)
{
  __shared__ __hip_bfloat16 lxb[32][136];
  __shared__ float lpart[32][8][2];
  __shared__ float lmr[32][2];
  __shared__ float lgb[128], lbeb[128];

  const int t = threadIdx.x;
  const int bb = blockIdx.x;
  int mode, row0;
  const float *in, *g, *be, *bo;
  const __hip_bfloat16* wb;
  if (bb < 79)       { mode = 0; row0 = bb * 32;         in = qin; g = qn_g; be = qn_b; wb = wball + WQB; bo = bq; }
  else if (bb < 277) { mode = 1; row0 = (bb - 79) * 32;  in = kin; g = kn_g; be = kn_b; wb = wball + WKB; bo = bk; }
  else               { mode = 2; row0 = (bb - 277) * 32; in = vin; g = vn_g; be = vn_b; wb = wball + WVB; bo = bv; }

  if (t < 128) { lgb[t] = g[t]; lbeb[t] = be[t]; }

  const int row = t & 31, seg = t >> 5;   // 8 segs x 16 d each
  int grow = row0 + row;
  size_t base, dstr;
  bool rvalid = true;
  if (mode == 0) { rvalid = (grow < NQ); base = (size_t)(rvalid ? grow : NQ - 1); dstr = NQ; }
  else { int n = grow / 1056, rr = grow - n * 1056; base = (size_t)n * 135168 + rr; dstr = 1056; }

  float xr[16];
  float s = 0.f, ss = 0.f;
  #pragma unroll
  for (int i = 0; i < 16; ++i) {
    float x = in[base + (size_t)(seg * 16 + i) * dstr];
    xr[i] = x; s += x; ss += x * x;
  }
  lpart[row][seg][0] = s; lpart[row][seg][1] = ss;
  __syncthreads();
  if (t < 32) {
    float S = 0.f, SS = 0.f;
    #pragma unroll
    for (int j = 0; j < 8; ++j) { S += lpart[t][j][0]; SS += lpart[t][j][1]; }
    float mean = S * (1.f / 128.f);
    float var  = SS * (1.f / 128.f) - mean * mean;
    lmr[t][0] = mean;
    lmr[t][1] = rsqrtf(fmaxf(var, 0.f) + 1e-5f);
  }
  __syncthreads();
  {
    float mean = lmr[row][0], rstd = lmr[row][1];
    #pragma unroll
    for (int i = 0; i < 16; ++i) {
      int d = seg * 16 + i;
      lxb[row][d] = __float2bfloat16((xr[i] - mean) * rstd * lgb[d] + lbeb[d]);
    }
  }
  __syncthreads();

  // GEMM: 32 rows x 128 out, K=128; 4 waves, each 32-wide o-chunk
  const int wid = t >> 6, lane = t & 63;
  const int n16 = lane & 15, quad = lane >> 4;
  const int ow = wid * 32;

  f32x4 acc[2][2] = {};
  for (int kt = 0; kt < 4; ++kt) {
    bf16x8 af[2];
    #pragma unroll
    for (int mi = 0; mi < 2; ++mi)
      af[mi] = *(const bf16x8*)&lxb[mi * 16 + n16][kt * 32 + quad * 8];
    #pragma unroll
    for (int ni = 0; ni < 2; ++ni) {
      bf16x8 bw = *(const bf16x8*)(wb + (size_t)(ow + ni * 16 + n16) * 128 + kt * 32 + quad * 8);
      #pragma unroll
      for (int mi = 0; mi < 2; ++mi)
        acc[mi][ni] = __builtin_amdgcn_mfma_f32_16x16x32_bf16(af[mi], bw, acc[mi][ni], 0, 0, 0);
    }
  }

  float bias[2];
  #pragma unroll
  for (int ni = 0; ni < 2; ++ni) bias[ni] = bo[ow + ni * 16 + n16];

  #pragma unroll
  for (int mi = 0; mi < 2; ++mi) {
    int gr0 = row0 + mi * 16 + quad * 4;
    if (mode == 2) {
      #pragma unroll
      for (int ni = 0; ni < 2; ++ni) {
        int o = ow + ni * 16 + n16;
        ushort4 v4;
        v4.x = bf16bits(acc[mi][ni][0] + bias[ni]);
        v4.y = bf16bits(acc[mi][ni][1] + bias[ni]);
        v4.z = bf16bits(acc[mi][ni][2] + bias[ni]);
        v4.w = bf16bits(acc[mi][ni][3] + bias[ni]);
        *(ushort4*)((unsigned short*)Vt + (size_t)o * NKK + gr0) = v4;
      }
    } else {
      #pragma unroll
      for (int rg = 0; rg < 4; ++rg) {
        int gr = gr0 + rg;
        if (mode != 0 || gr < NQ) {
          #pragma unroll
          for (int ni = 0; ni < 2; ++ni) {
            int o = ow + ni * 16 + n16;
            __hip_bfloat16 b16 = __float2bfloat16(acc[mi][ni][rg] + bias[ni]);
            if (mode == 0) Qp[(size_t)gr * 128 + o] = b16;
            else           Kp[(size_t)gr * 128 + o] = b16;
          }
        }
      }
    }
  }
}

// ============ flash attention v5: barrier-free waves ============
// r0-r3 evidence: dur == hbm_bytes / ~1.3 TB/s in every structure; the cap
// comes from the per-tile {issue -> dependent compute -> vmcnt(0) commit ->
// __syncthreads} chain (loads in flight only ~15% of the time, waves coupled
// by the barrier). Fix: each lane loads its W/vis values DIRECTLY in the
// MFMA fragment layout (16+16 scalar loads, same cache-line footprint; L2
// dedups the 4x head redundancy) -> no sc LDS, no commit, no vmcnt(0) drain,
// ZERO barriers in the k-loop. The 4 head-waves run fully independently;
// W/vis prefetch is a register pipeline with a whole loop body of cover.
__global__ __launch_bounds__(256, 4) void attn_kernel(
    const __hip_bfloat16* __restrict__ Qp,
    const __hip_bfloat16* __restrict__ Kp,
    const __hip_bfloat16* __restrict__ Vt,
    const float* __restrict__ Wl,
    const int* __restrict__ vis,
    float* __restrict__ Opart)
{
  __shared__ alignas(16) __hip_bfloat16 lp[NHEADS][ATQ * 64];   // 8192 B, per-wave, XOR-swizzled

  const int t = threadIdx.x;
  const int lane = t & 63;
  const int h = t >> 6;
  const int n16 = lane & 15;
  const int quad = lane >> 4;
  const int q0 = blockIdx.x * ATQ;
  const int split = blockIdx.y;
  const int ksplit = gridDim.y;
  const int tstart = (NTILES_TOTAL * split) / ksplit;
  const int ntiles = (NTILES_TOTAL * (split + 1)) / ksplit - tstart;

  bf16x8 aq;
  {
    int gqa = q0 + n16; if (gqa >= NQ) gqa = NQ - 1;
    aq = *(const bf16x8*)(Qp + (size_t)gqa * 128 + h * DHEAD + quad * 8);
  }

  // fragment-direct c addressing: this lane owns S rows q0+quad*4+r (r=0..3)
  // and cols k0 + ks*16 + n16 (ks=0..3)
  size_t cbase[4];
  #pragma unroll
  for (int r = 0; r < 4; ++r) {
    int gq = q0 + quad * 4 + r; if (gq >= NQ) gq = NQ - 1;
    cbase[r] = (size_t)gq * NKK + n16 + (size_t)tstart * TK;
  }

  // ones B-fragment: col 0 of D = row-sum of A (the softmax denominator)
  bf16x8 bones;
  {
    short one = (short)0x3F80;
    short val = (n16 == 0) ? one : (short)0;
    #pragma unroll
    for (int j = 0; j < 8; ++j) bones[j] = val;
  }

  float wr[16]; int vr[16]; float cc[16];

  auto issue_c = [&](int tile) {   // 32 scalar loads into regs, no waits
    size_t koff = (size_t)tile * TK;
    #pragma unroll
    for (int r = 0; r < 4; ++r) {
      #pragma unroll
      for (int ks = 0; ks < 4; ++ks) {
        wr[ks * 4 + r] = Wl[cbase[r] + koff + ks * 16];
        vr[ks * 4 + r] = vis[cbase[r] + koff + ks * 16];
      }
    }
  };
  auto convert_c = [&]() {         // first (and only) consumer of the loads
    #pragma unroll
    for (int i = 0; i < 16; ++i)
      cc[i] = vr[i] ? wr[i] * CSC : -1000.0f;   // exp2(-1000) == 0 (masked)
  };

  f32x4 o0 = {0.f,0.f,0.f,0.f}, o1 = {0.f,0.f,0.f,0.f}, o2 = {0.f,0.f,0.f,0.f};

  issue_c(0);
  convert_c();

  for (int kt = 0; kt < ntiles; ++kt) {
    const int k0 = (tstart + kt) * TK;
    if (kt + 1 < ntiles) issue_c(kt + 1);   // in flight across the whole body

    // S = Q K^T: K-fragments straight from global (L2/L3-hot)
    f32x4 s[4];
    #pragma unroll
    for (int ks = 0; ks < 4; ++ks) {
      bf16x8 bk = *(const bf16x8*)(Kp + (size_t)(k0 + ks * 16 + n16) * 128 + h * DHEAD + quad * 8);
      f32x4 z = {0.f, 0.f, 0.f, 0.f};
      s[ks] = __builtin_amdgcn_mfma_f32_16x16x32_bf16(aq, bk, z, 0, 0, 0);
    }

    // prefetch V-fragments: latency hides under the exp pass
    bf16x8 bv[2][2];
    #pragma unroll
    for (int kk = 0; kk < 2; ++kk) {
      bv[kk][0] = *(const bf16x8*)(Vt + (size_t)(h * DHEAD + n16) * NKK + k0 + kk * 32 + quad * 8);
      bv[kk][1] = *(const bf16x8*)(Vt + (size_t)(h * DHEAD + 16 + n16) * NKK + k0 + kk * 32 + quad * 8);
    }

    // p = exp2(s*c) (c>=0) or 0 (masked); c comes from registers now
    #pragma unroll
    for (int ks = 0; ks < 4; ++ks) {
      #pragma unroll
      for (int r = 0; r < 4; ++r) {
        int row = quad * 4 + r;
        float c = cc[ks * 4 + r];
        float tt = s[ks][r] * c;
        float arg = (c >= 0.f) ? tt : c;
        float p = exp2f(fminf(arg, 60.f));
        lp[h][row * 64 + ((ks * 16 + n16) ^ ((row & 7) << 3))] = __float2bfloat16(p);
      }
    }

    // O += P V ; l += P 1   (lp is per-wave: in-wave lgkmcnt ordering only)
    #pragma unroll
    for (int kk = 0; kk < 2; ++kk) {
      bf16x8 ap = *(const bf16x8*)&lp[h][n16 * 64 + ((kk * 32 + quad * 8) ^ ((n16 & 7) << 3))];
      o0 = __builtin_amdgcn_mfma_f32_16x16x32_bf16(ap, bv[kk][0], o0, 0, 0, 0);
      o1 = __builtin_amdgcn_mfma_f32_16x16x32_bf16(ap, bv[kk][1], o1, 0, 0, 0);
      o2 = __builtin_amdgcn_mfma_f32_16x16x32_bf16(ap, bones, o2, 0, 0, 0);
    }

    if (kt + 1 < ntiles) convert_c();   // loads had the whole body to land
  }

  // epilogue: unnormalized O + per-head l packed into Opart rows
  #pragma unroll
  for (int r = 0; r < 4; ++r) {
    int gq = q0 + quad * 4 + r;
    if (gq < NQ) {
      float* rowp = Opart + (size_t)split * OSPLIT_F + (size_t)gq * OROW_F;
      rowp[h * DHEAD + n16] = o0[r];
      rowp[h * DHEAD + 16 + n16] = o1[r];
      if (n16 == 0) rowp[128 + h] = o2[r];
    }
  }
}

// ============ merge + proj + preLN + MLP + postLN (MFMA), 16 q/block ============
__global__ __launch_bounds__(256) void mlp_kernel(
    const float* __restrict__ Opart, int ksplit,
    const float* __restrict__ skip,
    const __hip_bfloat16* __restrict__ wball,
    const float* __restrict__ bproj,
    const float* __restrict__ pre_g, const float* __restrict__ pre_b,
    const float* __restrict__ b1, const float* __restrict__ b2,
    const float* __restrict__ post_g, const float* __restrict__ post_b,
    float* __restrict__ out)
{
  __shared__ __hip_bfloat16 sab[16][136];
  __shared__ __hip_bfloat16 znb[16][136];
  __shared__ float znf[16][132];
  __shared__ __hip_bfloat16 hb[16][264];
  __shared__ float part[16][4][2];

  const __hip_bfloat16* wprojb = wball + WPROJB;
  const __hip_bfloat16* w1b    = wball + W1B;
  const __hip_bfloat16* w2b    = wball + W2B;

  const int t = threadIdx.x;
  const int q0 = blockIdx.x * TQ;

  // ---- merge k-splits (fixed softmax base: plain sums) ----
  {
    int row = t >> 4, c0 = (t & 15) * 8;
    int gq = q0 + row; int cq = gq < NQ ? gq : NQ - 1;
    int head = c0 >> 5;
    float ll = 0.f;
    float acc8[8] = {};
    for (int s = 0; s < ksplit; ++s) {
      const float* rp = Opart + (size_t)s * OSPLIT_F + (size_t)cq * OROW_F;
      ll += rp[128 + head];
      float4 a = *(const float4*)(rp + c0);
      float4 b = *(const float4*)(rp + c0 + 4);
      acc8[0] += a.x; acc8[1] += a.y; acc8[2] += a.z; acc8[3] += a.w;
      acc8[4] += b.x; acc8[5] += b.y; acc8[6] += b.z; acc8[7] += b.w;
    }
    float rll = 1.f / fmaxf(ll, 1e-30f);
    #pragma unroll
    for (int i = 0; i < 8; ++i)
      sab[row][c0 + i] = __float2bfloat16(acc8[i] * rll);
  }
  __syncthreads();

  const int wid = t >> 6, lane = t & 63;
  const int n16 = lane & 15, quad = lane >> 4;
  const int qrow0 = q0 + quad * 4;

  // ---- GEMM1: proj 128->128 ----
  f32x4 acc1[2] = {};
  for (int kt = 0; kt < 4; ++kt) {
    bf16x8 af = *(const bf16x8*)&sab[n16][kt * 32 + quad * 8];
    #pragma unroll
    for (int ni = 0; ni < 2; ++ni) {
      int o = wid * 32 + ni * 16 + n16;
      bf16x8 bw = *(const bf16x8*)(wprojb + (size_t)o * 128 + kt * 32 + quad * 8);
      acc1[ni] = __builtin_amdgcn_mfma_f32_16x16x32_bf16(af, bw, acc1[ni], 0, 0, 0);
    }
  }
  float z[2][4];
  #pragma unroll
  for (int ni = 0; ni < 2; ++ni) {
    int o = wid * 32 + ni * 16 + n16;
    float bo = bproj[o];
    if (qrow0 + 3 < NQ) {
      float4 sk = *(const float4*)(skip + (size_t)o * NQ + qrow0);
      z[ni][0] = acc1[ni][0] + bo + sk.x;
      z[ni][1] = acc1[ni][1] + bo + sk.y;
      z[ni][2] = acc1[ni][2] + bo + sk.z;
      z[ni][3] = acc1[ni][3] + bo + sk.w;
    } else {
      #pragma unroll
      for (int rg = 0; rg < 4; ++rg) {
        int cq = qrow0 + rg < NQ ? qrow0 + rg : NQ - 1;
        z[ni][rg] = acc1[ni][rg] + bo + skip[(size_t)o * NQ + cq];
      }
    }
  }
  #pragma unroll
  for (int rg = 0; rg < 4; ++rg) {
    float s = z[0][rg] + z[1][rg];
    float ss = z[0][rg] * z[0][rg] + z[1][rg] * z[1][rg];
    s += __shfl_xor(s, 1);  ss += __shfl_xor(ss, 1);
    s += __shfl_xor(s, 2);  ss += __shfl_xor(ss, 2);
    s += __shfl_xor(s, 4);  ss += __shfl_xor(ss, 4);
    s += __shfl_xor(s, 8);  ss += __shfl_xor(ss, 8);
    if (n16 == 0) { part[quad * 4 + rg][wid][0] = s; part[quad * 4 + rg][wid][1] = ss; }
  }
  __syncthreads();
  #pragma unroll
  for (int rg = 0; rg < 4; ++rg) {
    int row = quad * 4 + rg;
    float S  = part[row][0][0] + part[row][1][0] + part[row][2][0] + part[row][3][0];
    float SS = part[row][0][1] + part[row][1][1] + part[row][2][1] + part[row][3][1];
    float mean = S * (1.f / 128.f);
    float var  = SS * (1.f / 128.f) - mean * mean;
    float rstd = rsqrtf(fmaxf(var, 0.f) + 1e-5f);
    #pragma unroll
    for (int ni = 0; ni < 2; ++ni) {
      int o = wid * 32 + ni * 16 + n16;
      float zn = (z[ni][rg] - mean) * rstd * pre_g[o] + pre_b[o];
      znf[row][o] = zn;
      znb[row][o] = __float2bfloat16(zn);
    }
  }
  __syncthreads();

  // ---- GEMM2: 128 -> 256 + GELU ----
  f32x4 acc2[4] = {};
  for (int kt = 0; kt < 4; ++kt) {
    bf16x8 af = *(const bf16x8*)&znb[n16][kt * 32 + quad * 8];
    #pragma unroll
    for (int ni = 0; ni < 4; ++ni) {
      int j = wid * 64 + ni * 16 + n16;
      bf16x8 bw = *(const bf16x8*)(w1b + (size_t)j * 128 + kt * 32 + quad * 8);
      acc2[ni] = __builtin_amdgcn_mfma_f32_16x16x32_bf16(af, bw, acc2[ni], 0, 0, 0);
    }
  }
  #pragma unroll
  for (int ni = 0; ni < 4; ++ni) {
    int j = wid * 64 + ni * 16 + n16;
    float bj = b1[j];
    #pragma unroll
    for (int rg = 0; rg < 4; ++rg) {
      float a1 = acc2[ni][rg] + bj;
      hb[quad * 4 + rg][j] = __float2bfloat16(0.5f * a1 * (1.0f + erff(a1 * 0.70710678118654752f)));
    }
  }
  __syncthreads();

  // ---- GEMM3: 256 -> 128 + residual + postLN ----
  f32x4 acc3[2] = {};
  for (int kt = 0; kt < 8; ++kt) {
    bf16x8 af = *(const bf16x8*)&hb[n16][kt * 32 + quad * 8];
    #pragma unroll
    for (int ni = 0; ni < 2; ++ni) {
      int o = wid * 32 + ni * 16 + n16;
      bf16x8 bw = *(const bf16x8*)(w2b + (size_t)o * 256 + kt * 32 + quad * 8);
      acc3[ni] = __builtin_amdgcn_mfma_f32_16x16x32_bf16(af, bw, acc3[ni], 0, 0, 0);
    }
  }
  float y[2][4];
  #pragma unroll
  for (int ni = 0; ni < 2; ++ni) {
    int o = wid * 32 + ni * 16 + n16;
    float bo = b2[o];
    #pragma unroll
    for (int rg = 0; rg < 4; ++rg)
      y[ni][rg] = znf[quad * 4 + rg][o] + acc3[ni][rg] + bo;
  }
  #pragma unroll
  for (int rg = 0; rg < 4; ++rg) {
    float s = y[0][rg] + y[1][rg];
    float ss = y[0][rg] * y[0][rg] + y[1][rg] * y[1][rg];
    s += __shfl_xor(s, 1);  ss += __shfl_xor(ss, 1);
    s += __shfl_xor(s, 2);  ss += __shfl_xor(ss, 2);
    s += __shfl_xor(s, 4);  ss += __shfl_xor(ss, 4);
    s += __shfl_xor(s, 8);  ss += __shfl_xor(ss, 8);
    if (n16 == 0) { part[quad * 4 + rg][wid][0] = s; part[quad * 4 + rg][wid][1] = ss; }
  }
  __syncthreads();
  #pragma unroll
  for (int rg = 0; rg < 4; ++rg) {
    int row = quad * 4 + rg;
    float S  = part[row][0][0] + part[row][1][0] + part[row][2][0] + part[row][3][0];
    float SS = part[row][0][1] + part[row][1][1] + part[row][2][1] + part[row][3][1];
    float mean = S * (1.f / 128.f);
    float var  = SS * (1.f / 128.f) - mean * mean;
    float rstd = rsqrtf(fmaxf(var, 0.f) + 1e-5f);
    #pragma unroll
    for (int ni = 0; ni < 2; ++ni) {
      int o = wid * 32 + ni * 16 + n16;
      y[ni][rg] = (y[ni][rg] - mean) * rstd * post_g[o] + post_b[o];
    }
  }
  #pragma unroll
  for (int ni = 0; ni < 2; ++ni) {
    int o = wid * 32 + ni * 16 + n16;
    if (qrow0 + 3 < NQ) {
      *(float4*)(out + (size_t)o * NQ + qrow0) = make_float4(y[ni][0], y[ni][1], y[ni][2], y[ni][3]);
    } else {
      #pragma unroll
      for (int rg = 0; rg < 4; ++rg)
        if (qrow0 + rg < NQ) out[(size_t)o * NQ + qrow0 + rg] = y[ni][rg];
    }
  }
}

extern "C" void kernel_launch(void* const* d_in, const int* in_sizes, int n_in,
                              void* d_out, int out_size, void* d_ws, size_t ws_size,
                              hipStream_t stream) {
  if (ws_size < WS_REQ3) return;  // fail-safe (clean zero output)
  // ksplit back to <=8: r3 showed extra splits only add Opart/merge bytes
  int ksplit = (int)((ws_size - WS_OP) / (size_t)(OSPLIT_F * 4));
  if (ksplit > 8) ksplit = 8;
  if (ksplit < 3) ksplit = 3;

  const float* q     = (const float*)d_in[0];
  const float* k     = (const float*)d_in[1];
  const float* v     = (const float*)d_in[2];
  const float* Wl    = (const float*)d_in[3];
  const int*   vis   = (const int*)d_in[4];
  const float* skip  = (const float*)d_in[5];
  const float* qn_g  = (const float*)d_in[6];
  const float* qn_b  = (const float*)d_in[7];
  const float* kn_g  = (const float*)d_in[8];
  const float* kn_b  = (const float*)d_in[9];
  const float* vn_g  = (const float*)d_in[10];
  const float* vn_b  = (const float*)d_in[11];
  const float* wq    = (const float*)d_in[12];
  const float* bq    = (const float*)d_in[13];
  const float* wk    = (const float*)d_in[14];
  const float* bk    = (const float*)d_in[15];
  const float* wv    = (const float*)d_in[16];
  const float* bv    = (const float*)d_in[17];
  const float* wproj = (const float*)d_in[18];
  const float* bproj = (const float*)d_in[19];
  const float* pre_g = (const float*)d_in[20];
  const float* pre_b = (const float*)d_in[21];
  const float* w1    = (const float*)d_in[22];
  const float* b1    = (const float*)d_in[23];
  const float* w2    = (const float*)d_in[24];
  const float* b2    = (const float*)d_in[25];
  const float* post_g= (const float*)d_in[26];
  const float* post_b= (const float*)d_in[27];

  char* ws = (char*)d_ws;
  __hip_bfloat16* Qp = (__hip_bfloat16*)(ws + WS_QP);
  __hip_bfloat16* Kp = (__hip_bfloat16*)(ws + WS_KP);
  __hip_bfloat16* Vt = (__hip_bfloat16*)(ws + WS_VT);
  __hip_bfloat16* Wb = (__hip_bfloat16*)(ws + WS_WB);
  float* Opart = (float*)(ws + WS_OP);

  hipLaunchKernelGGL(wconv_kernel, dim3(128), dim3(256), 0, stream,
                     wq, wk, wv, wproj, w1, w2, Wb);

  hipLaunchKernelGGL(lnproj_kernel, dim3(475), dim3(256), 0, stream,
                     q, k, v, qn_g, qn_b, kn_g, kn_b, vn_g, vn_b,
                     Wb, bq, bk, bv, Qp, Kp, Vt);

  hipLaunchKernelGGL(attn_kernel, dim3(AQBLOCKS, ksplit), dim3(256), 0, stream,
                     Qp, Kp, Vt, Wl, vis, Opart);

  hipLaunchKernelGGL(mlp_kernel, dim3(QBLOCKS), dim3(256), 0, stream,
                     Opart, ksplit, skip, Wb, bproj, pre_g, pre_b,
                     b1, b2, post_g, post_b, (float*)d_out);
}

// Round 5
// 250.262 us; speedup vs baseline: 1.2116x; 1.2116x over previous
//
#include <hip/hip_runtime.h>
#include <hip/hip_bf16.h>

typedef __attribute__((ext_vector_type(8))) short bf16x8;
typedef __attribute__((ext_vector_type(4))) float f32x4;

#define NQ 2500
#define NKK 6336
#define NHEADS 4
#define DHEAD 32
// SCALE * log2(e): p = exp2(s * c)
#define CSC 0.25503482f
#define BIGNEG (-1.0e30f)

// workspace byte offsets
#define WS_QP 0
#define WS_KP 640000
#define WS_VT 2262016
#define WS_WB 3884032
#define WS_OP 4146176
// Opart: per split 2500 rows x 136 floats (128 O + 4 l per head)
#define OSPLIT_F 340000
#define OROW_F 136
#define WS_REQ3 8226176ULL

// bf16 weight element offsets inside WS_WB
#define WQB 0
#define WKB 16384
#define WVB 32768
#define WPROJB 49152
#define W1B 65536
#define W2B 98304

#define NTILES_TOTAL 99
#define TQ 16
#define ATQ 64
#define TK 64
#define QBLOCKS 157
#define AQBLOCKS 40

#define PSTR 72
#define ABSTR 68

__device__ __forceinline__ unsigned short bf16bits(float x) {
  union { __hip_bfloat16 h; unsigned short s; } cv;
  cv.h = __float2bfloat16(x);
  return cv.s;
}

// ============ weight fp32->bf16 conversion (once per launch) ============
__global__ __launch_bounds__(256) void wconv_kernel(
    const float* __restrict__ wq, const float* __restrict__ wk,
    const float* __restrict__ wv, const float* __restrict__ wproj,
    const float* __restrict__ w1, const float* __restrict__ w2,
    __hip_bfloat16* __restrict__ wb)
{
  int e = (blockIdx.x * 256 + threadIdx.x) * 4;
  const float* src; int off;
  if (e < 16384)      { src = wq;    off = e; }
  else if (e < 32768) { src = wk;    off = e - 16384; }
  else if (e < 49152) { src = wv;    off = e - 32768; }
  else if (e < 65536) { src = wproj; off = e - 49152; }
  else if (e < 98304) { src = w1;    off = e - 65536; }
  else                { src = w2;    off = e - 98304; }
  float4 v = *(const float4*)(src + off);
  ushort4 o4;
  o4.x = bf16bits(v.x); o4.y = bf16bits(v.y); o4.z = bf16bits(v.z); o4.w = bf16bits(v.w);
  *(ushort4*)((unsigned short*)wb + e) = o4;
}

// ============ lnproj: LN + 128x128 projection (MFMA), 32 rows/block, 256 thr ============
__global__ __launch_bounds__(256) void lnproj_kernel(
    const float* __restrict__ qin, const float* __restrict__ kin, const float* __restrict__ vin,
    const float* __restrict__ qn_g, const float* __restrict__ qn_b,
    const float* __restrict__ kn_g, const float* __restrict__ kn_b,
    const float* __restrict__ vn_g, const float* __restrict__ vn_b,
    const __hip_bfloat16* __restrict__ wball,
    const float* __restrict__ bq, const float* __restrict__ bk, const float* __restrict__ bv,
    __hip_bfloat16* __restrict__ Qp, __hip_bfloat16* __restrict__ Kp,
    __hip_bfloat16* __restrict__ Vt)
{
  __shared__ __hip_bfloat16 lxb[32][136];
  __shared__ float lpart[32][8][2];
  __shared__ float lmr[32][2];
  __shared__ float lgb[128], lbeb[128];

  const int t = threadIdx.x;
  const int bb = blockIdx.x;
  int mode, row0;
  const float *in, *g, *be, *bo;
  const __hip_bfloat16* wb;
  if (bb < 79)       { mode = 0; row0 = bb * 32;         in = qin; g = qn_g; be = qn_b; wb = wball + WQB; bo = bq; }
  else if (bb < 277) { mode = 1; row0 = (bb - 79) * 32;  in = kin; g = kn_g; be = kn_b; wb = wball + WKB; bo = bk; }
  else               { mode = 2; row0 = (bb - 277) * 32; in = vin; g = vn_g; be = vn_b; wb = wball + WVB; bo = bv; }

  if (t < 128) { lgb[t] = g[t]; lbeb[t] = be[t]; }

  const int row = t & 31, seg = t >> 5;   // 8 segs x 16 d each
  int grow = row0 + row;
  size_t base, dstr;
  bool rvalid = true;
  if (mode == 0) { rvalid = (grow < NQ); base = (size_t)(rvalid ? grow : NQ - 1); dstr = NQ; }
  else { int n = grow / 1056, rr = grow - n * 1056; base = (size_t)n * 135168 + rr; dstr = 1056; }

  float xr[16];
  float s = 0.f, ss = 0.f;
  #pragma unroll
  for (int i = 0; i < 16; ++i) {
    float x = in[base + (size_t)(seg * 16 + i) * dstr];
    xr[i] = x; s += x; ss += x * x;
  }
  lpart[row][seg][0] = s; lpart[row][seg][1] = ss;
  __syncthreads();
  if (t < 32) {
    float S = 0.f, SS = 0.f;
    #pragma unroll
    for (int j = 0; j < 8; ++j) { S += lpart[t][j][0]; SS += lpart[t][j][1]; }
    float mean = S * (1.f / 128.f);
    float var  = SS * (1.f / 128.f) - mean * mean;
    lmr[t][0] = mean;
    lmr[t][1] = rsqrtf(fmaxf(var, 0.f) + 1e-5f);
  }
  __syncthreads();
  {
    float mean = lmr[row][0], rstd = lmr[row][1];
    #pragma unroll
    for (int i = 0; i < 16; ++i) {
      int d = seg * 16 + i;
      lxb[row][d] = __float2bfloat16((xr[i] - mean) * rstd * lgb[d] + lbeb[d]);
    }
  }
  __syncthreads();

  // GEMM: 32 rows x 128 out, K=128; 4 waves, each 32-wide o-chunk
  const int wid = t >> 6, lane = t & 63;
  const int n16 = lane & 15, quad = lane >> 4;
  const int ow = wid * 32;

  f32x4 acc[2][2] = {};
  for (int kt = 0; kt < 4; ++kt) {
    bf16x8 af[2];
    #pragma unroll
    for (int mi = 0; mi < 2; ++mi)
      af[mi] = *(const bf16x8*)&lxb[mi * 16 + n16][kt * 32 + quad * 8];
    #pragma unroll
    for (int ni = 0; ni < 2; ++ni) {
      bf16x8 bw = *(const bf16x8*)(wb + (size_t)(ow + ni * 16 + n16) * 128 + kt * 32 + quad * 8);
      #pragma unroll
      for (int mi = 0; mi < 2; ++mi)
        acc[mi][ni] = __builtin_amdgcn_mfma_f32_16x16x32_bf16(af[mi], bw, acc[mi][ni], 0, 0, 0);
    }
  }

  float bias[2];
  #pragma unroll
  for (int ni = 0; ni < 2; ++ni) bias[ni] = bo[ow + ni * 16 + n16];

  #pragma unroll
  for (int mi = 0; mi < 2; ++mi) {
    int gr0 = row0 + mi * 16 + quad * 4;
    if (mode == 2) {
      #pragma unroll
      for (int ni = 0; ni < 2; ++ni) {
        int o = ow + ni * 16 + n16;
        ushort4 v4;
        v4.x = bf16bits(acc[mi][ni][0] + bias[ni]);
        v4.y = bf16bits(acc[mi][ni][1] + bias[ni]);
        v4.z = bf16bits(acc[mi][ni][2] + bias[ni]);
        v4.w = bf16bits(acc[mi][ni][3] + bias[ni]);
        *(ushort4*)((unsigned short*)Vt + (size_t)o * NKK + gr0) = v4;
      }
    } else {
      #pragma unroll
      for (int rg = 0; rg < 4; ++rg) {
        int gr = gr0 + rg;
        if (mode != 0 || gr < NQ) {
          #pragma unroll
          for (int ni = 0; ni < 2; ++ni) {
            int o = ow + ni * 16 + n16;
            __hip_bfloat16 b16 = __float2bfloat16(acc[mi][ni][rg] + bias[ni]);
            if (mode == 0) Qp[(size_t)gr * 128 + o] = b16;
            else           Kp[(size_t)gr * 128 + o] = b16;
          }
        }
      }
    }
  }
}

// ============ flash attention v6: ATQ=64 to halve K/V cache-path traffic ============
// r0-r4 model: dur == (L2-miss-path traffic) / ~5.5 TB/s. W/vis (127MB) is
// read-once and invariant; K/V re-read traffic = (NQ/ATQ) * full-K/V. r1's
// ATQ=32 -> ~250MB; this ATQ=64 (512 thr, 8 waves = 4 heads x 2 q-halves)
// -> ~127MB. Structure otherwise identical to the proven r0/r1 scheme:
// block-cooperative W/vis staging into sc (fp32, CSC/mask pre-applied),
// single-buffer + 2 barriers (64-row double buffer would exceed 64KB LDS).
__global__ __launch_bounds__(512, 2) void attn_kernel(
    const __hip_bfloat16* __restrict__ Qp,
    const __hip_bfloat16* __restrict__ Kp,
    const __hip_bfloat16* __restrict__ Vt,
    const float* __restrict__ Wl,
    const int* __restrict__ vis,
    float* __restrict__ Opart)
{
  __shared__ alignas(16) float sc[ATQ * ABSTR];                  // 17408 B
  __shared__ alignas(16) __hip_bfloat16 lp[8][32 * PSTR];        // 36864 B

  const int t = threadIdx.x;
  const int lane = t & 63;
  const int w = t >> 6;        // wave 0..7
  const int h = w & 3;         // head
  const int qh = w >> 2;       // q-half (0: rows 0-31, 1: rows 32-63)
  const int n16 = lane & 15;
  const int quad = lane >> 4;
  const int q0 = blockIdx.x * ATQ;
  const int split = blockIdx.y;
  const int ksplit = gridDim.y;
  const int tstart = (NTILES_TOTAL * split) / ksplit;
  const int ntiles = (NTILES_TOTAL * (split + 1)) / ksplit - tstart;

  bf16x8 aq[2];
  #pragma unroll
  for (int m = 0; m < 2; ++m) {
    int gqa = q0 + qh * 32 + m * 16 + n16; if (gqa >= NQ) gqa = NQ - 1;
    aq[m] = *(const bf16x8*)(Qp + (size_t)gqa * 128 + h * DHEAD + quad * 8);
  }

  const int qq = t >> 3, kkc = (t & 7) * 8;   // W/vis staging: 64 rows x 64 cols, 8/thread
  int gqe = q0 + qq; if (gqe >= NQ) gqe = NQ - 1;
  const size_t wbase = (size_t)gqe * NKK + kkc;

  // ones B-fragment: col 0 of D = row-sum of A (the softmax denominator)
  bf16x8 bones;
  {
    short one = (short)0x3F80;
    short val = (n16 == 0) ? one : (short)0;
    #pragma unroll
    for (int j = 0; j < 8; ++j) bones[j] = val;
  }

  float4 pw0, pw1; int4 pvs0, pvs1;

  auto issue = [&](int tile) {
    int k0 = (tstart + tile) * TK;
    pw0  = *(const float4*)(Wl + wbase + k0);
    pw1  = *(const float4*)(Wl + wbase + k0 + 4);
    pvs0 = *(const int4*)(vis + wbase + k0);
    pvs1 = *(const int4*)(vis + wbase + k0 + 4);
  };
  auto commit = [&]() {
    float4 c0, c1;
    c0.x = pvs0.x ? pw0.x * CSC : BIGNEG * pw0.x;
    c0.y = pvs0.y ? pw0.y * CSC : BIGNEG * pw0.y;
    c0.z = pvs0.z ? pw0.z * CSC : BIGNEG * pw0.z;
    c0.w = pvs0.w ? pw0.w * CSC : BIGNEG * pw0.w;
    c1.x = pvs1.x ? pw1.x * CSC : BIGNEG * pw1.x;
    c1.y = pvs1.y ? pw1.y * CSC : BIGNEG * pw1.y;
    c1.z = pvs1.z ? pw1.z * CSC : BIGNEG * pw1.z;
    c1.w = pvs1.w ? pw1.w * CSC : BIGNEG * pw1.w;
    *(float4*)&sc[qq * ABSTR + kkc] = c0;
    *(float4*)&sc[qq * ABSTR + kkc + 4] = c1;
  };

  f32x4 o[2][3];
  #pragma unroll
  for (int m = 0; m < 2; ++m)
    #pragma unroll
    for (int j = 0; j < 3; ++j)
      o[m][j] = f32x4{0.f, 0.f, 0.f, 0.f};

  issue(0);
  commit();
  __syncthreads();

  for (int kt = 0; kt < ntiles; ++kt) {
    const int k0 = (tstart + kt) * TK;
    if (kt + 1 < ntiles) issue(kt + 1);   // W/vis HBM loads in flight over compute

    // S = Q K^T: K-fragments straight from global (cache-hot; shared by both q-halves)
    f32x4 s[2][4];
    #pragma unroll
    for (int ks = 0; ks < 4; ++ks) {
      bf16x8 bk = *(const bf16x8*)(Kp + (size_t)(k0 + ks * 16 + n16) * 128 + h * DHEAD + quad * 8);
      f32x4 z = {0.f, 0.f, 0.f, 0.f};
      s[0][ks] = __builtin_amdgcn_mfma_f32_16x16x32_bf16(aq[0], bk, z, 0, 0, 0);
      s[1][ks] = __builtin_amdgcn_mfma_f32_16x16x32_bf16(aq[1], bk, z, 0, 0, 0);
    }

    // prefetch V-fragments so their latency hides under the exp pass
    bf16x8 bv[2][2];
    #pragma unroll
    for (int kk = 0; kk < 2; ++kk) {
      bv[kk][0] = *(const bf16x8*)(Vt + (size_t)(h * DHEAD + n16) * NKK + k0 + kk * 32 + quad * 8);
      bv[kk][1] = *(const bf16x8*)(Vt + (size_t)(h * DHEAD + 16 + n16) * NKK + k0 + kk * 32 + quad * 8);
    }

    // p = exp2(s*c) (c>=0) or exp2(c) (masked)
    #pragma unroll
    for (int m = 0; m < 2; ++m) {
      #pragma unroll
      for (int ks = 0; ks < 4; ++ks) {
        #pragma unroll
        for (int r = 0; r < 4; ++r) {
          int row = m * 16 + quad * 4 + r;           // 0..31 in this wave's slab
          float c = sc[(qh * 32 + row) * ABSTR + ks * 16 + n16];
          float tt = s[m][ks][r] * c;
          float arg = (c >= 0.f) ? tt : c;
          float p = exp2f(fminf(arg, 60.f));
          lp[w][row * PSTR + ks * 16 + n16] = __float2bfloat16(p);
        }
      }
    }

    // O += P V ; l += P 1  (lp slab is per-wave: in-wave lgkmcnt ordering only)
    #pragma unroll
    for (int kk = 0; kk < 2; ++kk) {
      #pragma unroll
      for (int m = 0; m < 2; ++m) {
        bf16x8 ap = *(const bf16x8*)&lp[w][(m * 16 + n16) * PSTR + kk * 32 + quad * 8];
        o[m][0] = __builtin_amdgcn_mfma_f32_16x16x32_bf16(ap, bv[kk][0], o[m][0], 0, 0, 0);
        o[m][1] = __builtin_amdgcn_mfma_f32_16x16x32_bf16(ap, bv[kk][1], o[m][1], 0, 0, 0);
        o[m][2] = __builtin_amdgcn_mfma_f32_16x16x32_bf16(ap, bones, o[m][2], 0, 0, 0);
      }
    }

    if (kt + 1 < ntiles) {
      __syncthreads();   // everyone done reading sc
      commit();
      __syncthreads();   // sc refilled for next tile
    }
  }

  // epilogue: unnormalized O + per-head l packed into Opart rows
  #pragma unroll
  for (int m = 0; m < 2; ++m) {
    #pragma unroll
    for (int r = 0; r < 4; ++r) {
      int gq = q0 + qh * 32 + m * 16 + quad * 4 + r;
      if (gq < NQ) {
        float* rowp = Opart + (size_t)split * OSPLIT_F + (size_t)gq * OROW_F;
        rowp[h * DHEAD + n16] = o[m][0][r];
        rowp[h * DHEAD + 16 + n16] = o[m][1][r];
        if (n16 == 0) rowp[128 + h] = o[m][2][r];
      }
    }
  }
}

// ============ merge + proj + preLN + MLP + postLN (MFMA), 16 q/block ============
__global__ __launch_bounds__(256) void mlp_kernel(
    const float* __restrict__ Opart, int ksplit,
    const float* __restrict__ skip,
    const __hip_bfloat16* __restrict__ wball,
    const float* __restrict__ bproj,
    const float* __restrict__ pre_g, const float* __restrict__ pre_b,
    const float* __restrict__ b1, const float* __restrict__ b2,
    const float* __restrict__ post_g, const float* __restrict__ post_b,
    float* __restrict__ out)
{
  __shared__ __hip_bfloat16 sab[16][136];
  __shared__ __hip_bfloat16 znb[16][136];
  __shared__ float znf[16][132];
  __shared__ __hip_bfloat16 hb[16][264];
  __shared__ float part[16][4][2];

  const __hip_bfloat16* wprojb = wball + WPROJB;
  const __hip_bfloat16* w1b    = wball + W1B;
  const __hip_bfloat16* w2b    = wball + W2B;

  const int t = threadIdx.x;
  const int q0 = blockIdx.x * TQ;

  // ---- merge k-splits (fixed softmax base: plain sums) ----
  {
    int row = t >> 4, c0 = (t & 15) * 8;
    int gq = q0 + row; int cq = gq < NQ ? gq : NQ - 1;
    int head = c0 >> 5;
    float ll = 0.f;
    float acc8[8] = {};
    for (int s = 0; s < ksplit; ++s) {
      const float* rp = Opart + (size_t)s * OSPLIT_F + (size_t)cq * OROW_F;
      ll += rp[128 + head];
      float4 a = *(const float4*)(rp + c0);
      float4 b = *(const float4*)(rp + c0 + 4);
      acc8[0] += a.x; acc8[1] += a.y; acc8[2] += a.z; acc8[3] += a.w;
      acc8[4] += b.x; acc8[5] += b.y; acc8[6] += b.z; acc8[7] += b.w;
    }
    float rll = 1.f / fmaxf(ll, 1e-30f);
    #pragma unroll
    for (int i = 0; i < 8; ++i)
      sab[row][c0 + i] = __float2bfloat16(acc8[i] * rll);
  }
  __syncthreads();

  const int wid = t >> 6, lane = t & 63;
  const int n16 = lane & 15, quad = lane >> 4;
  const int qrow0 = q0 + quad * 4;

  // ---- GEMM1: proj 128->128 ----
  f32x4 acc1[2] = {};
  for (int kt = 0; kt < 4; ++kt) {
    bf16x8 af = *(const bf16x8*)&sab[n16][kt * 32 + quad * 8];
    #pragma unroll
    for (int ni = 0; ni < 2; ++ni) {
      int o = wid * 32 + ni * 16 + n16;
      bf16x8 bw = *(const bf16x8*)(wprojb + (size_t)o * 128 + kt * 32 + quad * 8);
      acc1[ni] = __builtin_amdgcn_mfma_f32_16x16x32_bf16(af, bw, acc1[ni], 0, 0, 0);
    }
  }
  float z[2][4];
  #pragma unroll
  for (int ni = 0; ni < 2; ++ni) {
    int o = wid * 32 + ni * 16 + n16;
    float bo = bproj[o];
    if (qrow0 + 3 < NQ) {
      float4 sk = *(const float4*)(skip + (size_t)o * NQ + qrow0);
      z[ni][0] = acc1[ni][0] + bo + sk.x;
      z[ni][1] = acc1[ni][1] + bo + sk.y;
      z[ni][2] = acc1[ni][2] + bo + sk.z;
      z[ni][3] = acc1[ni][3] + bo + sk.w;
    } else {
      #pragma unroll
      for (int rg = 0; rg < 4; ++rg) {
        int cq = qrow0 + rg < NQ ? qrow0 + rg : NQ - 1;
        z[ni][rg] = acc1[ni][rg] + bo + skip[(size_t)o * NQ + cq];
      }
    }
  }
  #pragma unroll
  for (int rg = 0; rg < 4; ++rg) {
    float s = z[0][rg] + z[1][rg];
    float ss = z[0][rg] * z[0][rg] + z[1][rg] * z[1][rg];
    s += __shfl_xor(s, 1);  ss += __shfl_xor(ss, 1);
    s += __shfl_xor(s, 2);  ss += __shfl_xor(ss, 2);
    s += __shfl_xor(s, 4);  ss += __shfl_xor(ss, 4);
    s += __shfl_xor(s, 8);  ss += __shfl_xor(ss, 8);
    if (n16 == 0) { part[quad * 4 + rg][wid][0] = s; part[quad * 4 + rg][wid][1] = ss; }
  }
  __syncthreads();
  #pragma unroll
  for (int rg = 0; rg < 4; ++rg) {
    int row = quad * 4 + rg;
    float S  = part[row][0][0] + part[row][1][0] + part[row][2][0] + part[row][3][0];
    float SS = part[row][0][1] + part[row][1][1] + part[row][2][1] + part[row][3][1];
    float mean = S * (1.f / 128.f);
    float var  = SS * (1.f / 128.f) - mean * mean;
    float rstd = rsqrtf(fmaxf(var, 0.f) + 1e-5f);
    #pragma unroll
    for (int ni = 0; ni < 2; ++ni) {
      int o = wid * 32 + ni * 16 + n16;
      float zn = (z[ni][rg] - mean) * rstd * pre_g[o] + pre_b[o];
      znf[row][o] = zn;
      znb[row][o] = __float2bfloat16(zn);
    }
  }
  __syncthreads();

  // ---- GEMM2: 128 -> 256 + GELU ----
  f32x4 acc2[4] = {};
  for (int kt = 0; kt < 4; ++kt) {
    bf16x8 af = *(const bf16x8*)&znb[n16][kt * 32 + quad * 8];
    #pragma unroll
    for (int ni = 0; ni < 4; ++ni) {
      int j = wid * 64 + ni * 16 + n16;
      bf16x8 bw = *(const bf16x8*)(w1b + (size_t)j * 128 + kt * 32 + quad * 8);
      acc2[ni] = __builtin_amdgcn_mfma_f32_16x16x32_bf16(af, bw, acc2[ni], 0, 0, 0);
    }
  }
  #pragma unroll
  for (int ni = 0; ni < 4; ++ni) {
    int j = wid * 64 + ni * 16 + n16;
    float bj = b1[j];
    #pragma unroll
    for (int rg = 0; rg < 4; ++rg) {
      float a1 = acc2[ni][rg] + bj;
      hb[quad * 4 + rg][j] = __float2bfloat16(0.5f * a1 * (1.0f + erff(a1 * 0.70710678118654752f)));
    }
  }
  __syncthreads();

  // ---- GEMM3: 256 -> 128 + residual + postLN ----
  f32x4 acc3[2] = {};
  for (int kt = 0; kt < 8; ++kt) {
    bf16x8 af = *(const bf16x8*)&hb[n16][kt * 32 + quad * 8];
    #pragma unroll
    for (int ni = 0; ni < 2; ++ni) {
      int o = wid * 32 + ni * 16 + n16;
      bf16x8 bw = *(const bf16x8*)(w2b + (size_t)o * 256 + kt * 32 + quad * 8);
      acc3[ni] = __builtin_amdgcn_mfma_f32_16x16x32_bf16(af, bw, acc3[ni], 0, 0, 0);
    }
  }
  float y[2][4];
  #pragma unroll
  for (int ni = 0; ni < 2; ++ni) {
    int o = wid * 32 + ni * 16 + n16;
    float bo = b2[o];
    #pragma unroll
    for (int rg = 0; rg < 4; ++rg)
      y[ni][rg] = znf[quad * 4 + rg][o] + acc3[ni][rg] + bo;
  }
  #pragma unroll
  for (int rg = 0; rg < 4; ++rg) {
    float s = y[0][rg] + y[1][rg];
    float ss = y[0][rg] * y[0][rg] + y[1][rg] * y[1][rg];
    s += __shfl_xor(s, 1);  ss += __shfl_xor(ss, 1);
    s += __shfl_xor(s, 2);  ss += __shfl_xor(ss, 2);
    s += __shfl_xor(s, 4);  ss += __shfl_xor(ss, 4);
    s += __shfl_xor(s, 8);  ss += __shfl_xor(ss, 8);
    if (n16 == 0) { part[quad * 4 + rg][wid][0] = s; part[quad * 4 + rg][wid][1] = ss; }
  }
  __syncthreads();
  #pragma unroll
  for (int rg = 0; rg < 4; ++rg) {
    int row = quad * 4 + rg;
    float S  = part[row][0][0] + part[row][1][0] + part[row][2][0] + part[row][3][0];
    float SS = part[row][0][1] + part[row][1][1] + part[row][2][1] + part[row][3][1];
    float mean = S * (1.f / 128.f);
    float var  = SS * (1.f / 128.f) - mean * mean;
    float rstd = rsqrtf(fmaxf(var, 0.f) + 1e-5f);
    #pragma unroll
    for (int ni = 0; ni < 2; ++ni) {
      int o = wid * 32 + ni * 16 + n16;
      y[ni][rg] = (y[ni][rg] - mean) * rstd * post_g[o] + post_b[o];
    }
  }
  #pragma unroll
  for (int ni = 0; ni < 2; ++ni) {
    int o = wid * 32 + ni * 16 + n16;
    if (qrow0 + 3 < NQ) {
      *(float4*)(out + (size_t)o * NQ + qrow0) = make_float4(y[ni][0], y[ni][1], y[ni][2], y[ni][3]);
    } else {
      #pragma unroll
      for (int rg = 0; rg < 4; ++rg)
        if (qrow0 + rg < NQ) out[(size_t)o * NQ + qrow0 + rg] = y[ni][rg];
    }
  }
}

extern "C" void kernel_launch(void* const* d_in, const int* in_sizes, int n_in,
                              void* d_out, int out_size, void* d_ws, size_t ws_size,
                              hipStream_t stream) {
  if (ws_size < WS_REQ3) return;  // fail-safe (clean zero output)
  // k-split: total K/V cache traffic is ksplit-invariant at fixed ATQ;
  // more splits only add grid parallelism + Opart bytes. Cap 12.
  int ksplit = (int)((ws_size - WS_OP) / (size_t)(OSPLIT_F * 4));
  if (ksplit > 12) ksplit = 12;
  if (ksplit < 3)  ksplit = 3;

  const float* q     = (const float*)d_in[0];
  const float* k     = (const float*)d_in[1];
  const float* v     = (const float*)d_in[2];
  const float* Wl    = (const float*)d_in[3];
  const int*   vis   = (const int*)d_in[4];
  const float* skip  = (const float*)d_in[5];
  const float* qn_g  = (const float*)d_in[6];
  const float* qn_b  = (const float*)d_in[7];
  const float* kn_g  = (const float*)d_in[8];
  const float* kn_b  = (const float*)d_in[9];
  const float* vn_g  = (const float*)d_in[10];
  const float* vn_b  = (const float*)d_in[11];
  const float* wq    = (const float*)d_in[12];
  const float* bq    = (const float*)d_in[13];
  const float* wk    = (const float*)d_in[14];
  const float* bk    = (const float*)d_in[15];
  const float* wv    = (const float*)d_in[16];
  const float* bv    = (const float*)d_in[17];
  const float* wproj = (const float*)d_in[18];
  const float* bproj = (const float*)d_in[19];
  const float* pre_g = (const float*)d_in[20];
  const float* pre_b = (const float*)d_in[21];
  const float* w1    = (const float*)d_in[22];
  const float* b1    = (const float*)d_in[23];
  const float* w2    = (const float*)d_in[24];
  const float* b2    = (const float*)d_in[25];
  const float* post_g= (const float*)d_in[26];
  const float* post_b= (const float*)d_in[27];

  char* ws = (char*)d_ws;
  __hip_bfloat16* Qp = (__hip_bfloat16*)(ws + WS_QP);
  __hip_bfloat16* Kp = (__hip_bfloat16*)(ws + WS_KP);
  __hip_bfloat16* Vt = (__hip_bfloat16*)(ws + WS_VT);
  __hip_bfloat16* Wb = (__hip_bfloat16*)(ws + WS_WB);
  float* Opart = (float*)(ws + WS_OP);

  hipLaunchKernelGGL(wconv_kernel, dim3(128), dim3(256), 0, stream,
                     wq, wk, wv, wproj, w1, w2, Wb);

  hipLaunchKernelGGL(lnproj_kernel, dim3(475), dim3(256), 0, stream,
                     q, k, v, qn_g, qn_b, kn_g, kn_b, vn_g, vn_b,
                     Wb, bq, bk, bv, Qp, Kp, Vt);

  hipLaunchKernelGGL(attn_kernel, dim3(AQBLOCKS, ksplit), dim3(512), 0, stream,
                     Qp, Kp, Vt, Wl, vis, Opart);

  hipLaunchKernelGGL(mlp_kernel, dim3(QBLOCKS), dim3(256), 0, stream,
                     Opart, ksplit, skip, Wb, bproj, pre_g, pre_b,
                     b1, b2, post_g, post_b, (float*)d_out);
}

// Round 6
// 248.581 us; speedup vs baseline: 1.2198x; 1.0068x over previous
//
#include <hip/hip_runtime.h>
#include <hip/hip_bf16.h>

typedef __attribute__((ext_vector_type(8))) short bf16x8;
typedef __attribute__((ext_vector_type(4))) float f32x4;

#define NQ 2500
#define NKK 6336
#define NHEADS 4
#define DHEAD 32
// SCALE * log2(e): p = exp2(s * c)
#define CSC 0.25503482f
#define BIGNEG (-1.0e30f)

// workspace byte offsets
#define WS_QP 0
#define WS_KP 640000
#define WS_VT 2262016
#define WS_WB 3884032
#define WS_OP 4146176
// Opart: per split 2500 rows x 136 floats (128 O + 4 l per head)
#define OSPLIT_F 340000
#define OROW_F 136
#define WS_REQ3 8226176ULL

// bf16 weight element offsets inside WS_WB
#define WQB 0
#define WKB 16384
#define WVB 32768
#define WPROJB 49152
#define W1B 65536
#define W2B 98304

#define NTILES_TOTAL 99
#define TQ 16
#define ATQ 32
#define TK 64
#define QBLOCKS 157
#define AQBLOCKS 79

#define PSTR 72
#define QSTR 36   // scT row stride (floats), mult of 4 for b128-aligned reads

__device__ __forceinline__ unsigned short bf16bits(float x) {
  union { __hip_bfloat16 h; unsigned short s; } cv;
  cv.h = __float2bfloat16(x);
  return cv.s;
}

// fast RNE fp32->bf16 for known-finite non-NaN values (P = exp2 result)
__device__ __forceinline__ unsigned short fastbf16(float x) {
  union { float f; unsigned int u; } c; c.f = x;
  unsigned int r = c.u + 0x7fffu + ((c.u >> 16) & 1u);
  return (unsigned short)(r >> 16);
}

// ============ weight fp32->bf16 conversion (once per launch) ============
__global__ __launch_bounds__(256) void wconv_kernel(
    const float* __restrict__ wq, const float* __restrict__ wk,
    const float* __restrict__ wv, const float* __restrict__ wproj,
    const float* __restrict__ w1, const float* __restrict__ w2,
    __hip_bfloat16* __restrict__ wb)
{
  int e = (blockIdx.x * 256 + threadIdx.x) * 4;
  const float* src; int off;
  if (e < 16384)      { src = wq;    off = e; }
  else if (e < 32768) { src = wk;    off = e - 16384; }
  else if (e < 49152) { src = wv;    off = e - 32768; }
  else if (e < 65536) { src = wproj; off = e - 49152; }
  else if (e < 98304) { src = w1;    off = e - 65536; }
  else                { src = w2;    off = e - 98304; }
  float4 v = *(const float4*)(src + off);
  ushort4 o4;
  o4.x = bf16bits(v.x); o4.y = bf16bits(v.y); o4.z = bf16bits(v.z); o4.w = bf16bits(v.w);
  *(ushort4*)((unsigned short*)wb + e) = o4;
}

// ============ lnproj: LN + 128x128 projection (MFMA), 32 rows/block, 256 thr ============
__global__ __launch_bounds__(256) void lnproj_kernel(
    const float* __restrict__ qin, const float* __restrict__ kin, const float* __restrict__ vin,
    const float* __restrict__ qn_g, const float* __restrict__ qn_b,
    const float* __restrict__ kn_g, const float* __restrict__ kn_b,
    const float* __restrict__ vn_g, const float* __restrict__ vn_b,
    const __hip_bfloat16* __restrict__ wball,
    const float* __restrict__ bq, const float* __restrict__ bk, const float* __restrict__ bv,
    __hip_bfloat16* __restrict__ Qp, __hip_bfloat16* __restrict__ Kp,
    __hip_bfloat16* __restrict__ Vt)
{
  __shared__ __hip_bfloat16 lxb[32][136];
  __shared__ float lpart[32][8][2];
  __shared__ float lmr[32][2];
  __shared__ float lgb[128], lbeb[128];

  const int t = threadIdx.x;
  const int bb = blockIdx.x;
  int mode, row0;
  const float *in, *g, *be, *bo;
  const __hip_bfloat16* wb;
  if (bb < 79)       { mode = 0; row0 = bb * 32;         in = qin; g = qn_g; be = qn_b; wb = wball + WQB; bo = bq; }
  else if (bb < 277) { mode = 1; row0 = (bb - 79) * 32;  in = kin; g = kn_g; be = kn_b; wb = wball + WKB; bo = bk; }
  else               { mode = 2; row0 = (bb - 277) * 32; in = vin; g = vn_g; be = vn_b; wb = wball + WVB; bo = bv; }

  if (t < 128) { lgb[t] = g[t]; lbeb[t] = be[t]; }

  const int row = t & 31, seg = t >> 5;   // 8 segs x 16 d each
  int grow = row0 + row;
  size_t base, dstr;
  bool rvalid = true;
  if (mode == 0) { rvalid = (grow < NQ); base = (size_t)(rvalid ? grow : NQ - 1); dstr = NQ; }
  else { int n = grow / 1056, rr = grow - n * 1056; base = (size_t)n * 135168 + rr; dstr = 1056; }

  float xr[16];
  float s = 0.f, ss = 0.f;
  #pragma unroll
  for (int i = 0; i < 16; ++i) {
    float x = in[base + (size_t)(seg * 16 + i) * dstr];
    xr[i] = x; s += x; ss += x * x;
  }
  lpart[row][seg][0] = s; lpart[row][seg][1] = ss;
  __syncthreads();
  if (t < 32) {
    float S = 0.f, SS = 0.f;
    #pragma unroll
    for (int j = 0; j < 8; ++j) { S += lpart[t][j][0]; SS += lpart[t][j][1]; }
    float mean = S * (1.f / 128.f);
    float var  = SS * (1.f / 128.f) - mean * mean;
    lmr[t][0] = mean;
    lmr[t][1] = rsqrtf(fmaxf(var, 0.f) + 1e-5f);
  }
  __syncthreads();
  {
    float mean = lmr[row][0], rstd = lmr[row][1];
    #pragma unroll
    for (int i = 0; i < 16; ++i) {
      int d = seg * 16 + i;
      lxb[row][d] = __float2bfloat16((xr[i] - mean) * rstd * lgb[d] + lbeb[d]);
    }
  }
  __syncthreads();

  // GEMM: 32 rows x 128 out, K=128; 4 waves, each 32-wide o-chunk
  const int wid = t >> 6, lane = t & 63;
  const int n16 = lane & 15, quad = lane >> 4;
  const int ow = wid * 32;

  f32x4 acc[2][2] = {};
  for (int kt = 0; kt < 4; ++kt) {
    bf16x8 af[2];
    #pragma unroll
    for (int mi = 0; mi < 2; ++mi)
      af[mi] = *(const bf16x8*)&lxb[mi * 16 + n16][kt * 32 + quad * 8];
    #pragma unroll
    for (int ni = 0; ni < 2; ++ni) {
      bf16x8 bw = *(const bf16x8*)(wb + (size_t)(ow + ni * 16 + n16) * 128 + kt * 32 + quad * 8);
      #pragma unroll
      for (int mi = 0; mi < 2; ++mi)
        acc[mi][ni] = __builtin_amdgcn_mfma_f32_16x16x32_bf16(af[mi], bw, acc[mi][ni], 0, 0, 0);
    }
  }

  float bias[2];
  #pragma unroll
  for (int ni = 0; ni < 2; ++ni) bias[ni] = bo[ow + ni * 16 + n16];

  #pragma unroll
  for (int mi = 0; mi < 2; ++mi) {
    int gr0 = row0 + mi * 16 + quad * 4;
    if (mode == 2) {
      #pragma unroll
      for (int ni = 0; ni < 2; ++ni) {
        int o = ow + ni * 16 + n16;
        ushort4 v4;
        v4.x = bf16bits(acc[mi][ni][0] + bias[ni]);
        v4.y = bf16bits(acc[mi][ni][1] + bias[ni]);
        v4.z = bf16bits(acc[mi][ni][2] + bias[ni]);
        v4.w = bf16bits(acc[mi][ni][3] + bias[ni]);
        *(ushort4*)((unsigned short*)Vt + (size_t)o * NKK + gr0) = v4;
      }
    } else {
      #pragma unroll
      for (int rg = 0; rg < 4; ++rg) {
        int gr = gr0 + rg;
        if (mode != 0 || gr < NQ) {
          #pragma unroll
          for (int ni = 0; ni < 2; ++ni) {
            int o = ow + ni * 16 + n16;
            __hip_bfloat16 b16 = __float2bfloat16(acc[mi][ni][rg] + bias[ni]);
            if (mode == 0) Qp[(size_t)gr * 128 + o] = b16;
            else           Kp[(size_t)gr * 128 + o] = b16;
          }
        }
      }
    }
  }
}

// ============ flash attention v7: VALU-diet ============
// r0-r5 accounting: ~935 VALU instr per wave-tile (exp2f lowering ~6/elem,
// slow bf16 cvt ~6/elem, per-element LDS addressing, 64-bit addr math) is the
// measured bottleneck -- occupancy/traffic/barrier changes all left dur at
// 71us. This version keeps r1's proven structure and cuts per-element ops:
// raw v_exp_f32 (1 op), fast RNE bf16 pack (4 ops, no NaN path), sc stored
// TRANSPOSED [k][q] so c-values read as one ds_read_b128 per 4 elements
// (XOR chunk swizzle for bank spread), lp addressed via one per-lane base +
// compile-time immediate offsets, strength-reduced global pointers.
__global__ __launch_bounds__(256, 3) void attn_kernel(
    const __hip_bfloat16* __restrict__ Qp,
    const __hip_bfloat16* __restrict__ Kp,
    const __hip_bfloat16* __restrict__ Vt,
    const float* __restrict__ Wl,
    const int* __restrict__ vis,
    float* __restrict__ Opart)
{
  __shared__ alignas(16) float scT[2][TK * QSTR];                 // 2 x 9216 B, [k][q] + chunk swizzle
  __shared__ alignas(16) __hip_bfloat16 lp[NHEADS][ATQ * PSTR];   // 18432 B, per-wave slabs

  const int t = threadIdx.x;
  const int lane = t & 63;
  const int h = t >> 6;
  const int n16 = lane & 15;
  const int quad = lane >> 4;
  const int q0 = blockIdx.x * ATQ;
  const int split = blockIdx.y;
  const int ksplit = gridDim.y;
  const int tstart = (NTILES_TOTAL * split) / ksplit;
  const int ntiles = (NTILES_TOTAL * (split + 1)) / ksplit - tstart;

  bf16x8 aq[2];
  #pragma unroll
  for (int m = 0; m < 2; ++m) {
    int gqa = q0 + m * 16 + n16; if (gqa >= NQ) gqa = NQ - 1;
    aq[m] = *(const bf16x8*)(Qp + (size_t)gqa * 128 + h * DHEAD + quad * 8);
  }

  // W/vis staging ids: 32 rows x 64 cols, 8 elems/thread
  const int qq = t >> 3, kkc = (t & 7) * 8;
  int gqe = q0 + qq; if (gqe >= NQ) gqe = NQ - 1;
  const float* wlp = Wl  + (size_t)gqe * NKK + kkc + (size_t)tstart * TK;
  const int*   vsp = vis + (size_t)gqe * NKK + kkc + (size_t)tstart * TK;

  // strength-reduced K/V pointers (advance by fixed stride per tile)
  const __hip_bfloat16* kp[4];
  #pragma unroll
  for (int ks = 0; ks < 4; ++ks)
    kp[ks] = Kp + (size_t)(tstart * TK + ks * 16 + n16) * 128 + h * DHEAD + quad * 8;
  const __hip_bfloat16* vp0 = Vt + (size_t)(h * DHEAD + n16) * NKK + tstart * TK + quad * 8;
  const __hip_bfloat16* vp1 = vp0 + (size_t)16 * NKK;

  // per-lane LDS bases (all loop accesses are base + compile-time offset)
  unsigned short* lpw = (unsigned short*)&lp[h][quad * 4 * PSTR + n16];      // write: +m*1152 + r*72 + ks*16
  const unsigned short* lpr = (const unsigned short*)&lp[h][n16 * PSTR + quad * 8]; // read: +m*1152 + kk*32
  // scT write base: logical (k=kkc+i, q=qq); phys chunk = (qq>>2) ^ (kkc>>3)
  const int swidx = kkc * QSTR + (((qq >> 2) ^ (kkc >> 3)) << 2) + (qq & 3);
  float* swA = &scT[0][swidx];
  float* swB = &scT[1][swidx];
  // scT read bases (row part); chunk xor resolved per (m,ks) in the loop
  const float* scrA = &scT[0][n16 * QSTR];
  const float* scrB = &scT[1][n16 * QSTR];
  const int hi8 = n16 >> 3;

  // ones B-fragment: col 0 of D = row-sum of A (the softmax denominator)
  bf16x8 bones;
  {
    short one = (short)0x3F80;
    short val = (n16 == 0) ? one : (short)0;
    #pragma unroll
    for (int j = 0; j < 8; ++j) bones[j] = val;
  }

  float4 pw0, pw1; int4 pvs0, pvs1;

  auto issue = [&]() {
    pw0  = *(const float4*)(wlp);
    pw1  = *(const float4*)(wlp + 4);
    pvs0 = *(const int4*)(vsp);
    pvs1 = *(const int4*)(vsp + 4);
    wlp += TK; vsp += TK;
  };
  auto commit = [&](float* swp) {
    float c[8];
    c[0] = pvs0.x ? pw0.x * CSC : BIGNEG * pw0.x;
    c[1] = pvs0.y ? pw0.y * CSC : BIGNEG * pw0.y;
    c[2] = pvs0.z ? pw0.z * CSC : BIGNEG * pw0.z;
    c[3] = pvs0.w ? pw0.w * CSC : BIGNEG * pw0.w;
    c[4] = pvs1.x ? pw1.x * CSC : BIGNEG * pw1.x;
    c[5] = pvs1.y ? pw1.y * CSC : BIGNEG * pw1.y;
    c[6] = pvs1.z ? pw1.z * CSC : BIGNEG * pw1.z;
    c[7] = pvs1.w ? pw1.w * CSC : BIGNEG * pw1.w;
    #pragma unroll
    for (int i = 0; i < 8; ++i)
      swp[i * QSTR] = c[i];    // k advances by 1 per i; chunk swizzle constant per thread
  };

  f32x4 o[2][3];
  #pragma unroll
  for (int m = 0; m < 2; ++m)
    #pragma unroll
    for (int j = 0; j < 3; ++j)
      o[m][j] = f32x4{0.f, 0.f, 0.f, 0.f};

  issue();
  commit(swA);
  __syncthreads();

  for (int kt = 0; kt < ntiles; ++kt) {
    const float* scp = (kt & 1) ? scrB : scrA;
    float* swp = (kt & 1) ? swA : swB;     // next tile's buffer
    if (kt + 1 < ntiles) issue();          // HBM loads in flight over whole body

    // S = Q K^T (K straight from global, L2-hot)
    f32x4 s[2][4];
    #pragma unroll
    for (int ks = 0; ks < 4; ++ks) {
      bf16x8 bk = *(const bf16x8*)kp[ks];
      kp[ks] += TK * 128;
      f32x4 z = {0.f, 0.f, 0.f, 0.f};
      s[0][ks] = __builtin_amdgcn_mfma_f32_16x16x32_bf16(aq[0], bk, z, 0, 0, 0);
      s[1][ks] = __builtin_amdgcn_mfma_f32_16x16x32_bf16(aq[1], bk, z, 0, 0, 0);
    }

    // prefetch V-fragments: latency hides under the exp pass
    bf16x8 bv[2][2];
    #pragma unroll
    for (int kk = 0; kk < 2; ++kk) {
      bv[kk][0] = *(const bf16x8*)(vp0 + kk * 32);
      bv[kk][1] = *(const bf16x8*)(vp1 + kk * 32);
    }
    vp0 += TK; vp1 += TK;

    // p = exp2(s*c) (c>=0) or exp2(c) (masked); c read as float4 from scT
    #pragma unroll
    for (int m = 0; m < 2; ++m) {
      #pragma unroll
      for (int ks = 0; ks < 4; ++ks) {
        int ch = (m * 4 + quad) ^ (2 * ks + hi8);        // phys chunk for q-chunk (m*4+quad), k-row ks*16+n16
        float4 c4 = *(const float4*)(scp + ks * 16 * QSTR + ch * 4);
        #pragma unroll
        for (int r = 0; r < 4; ++r) {
          float cr = (r == 0) ? c4.x : (r == 1) ? c4.y : (r == 2) ? c4.z : c4.w;
          float tt = fminf(s[m][ks][r] * cr, 60.f);
          float arg = (cr >= 0.f) ? tt : cr;
          float p;
          asm("v_exp_f32 %0, %1" : "=v"(p) : "v"(arg));
          lpw[m * 1152 + r * 72 + ks * 16] = fastbf16(p);
        }
      }
    }

    // O += P V ; l += P 1  (lp slab per-wave: in-wave lgkmcnt ordering only)
    #pragma unroll
    for (int kk = 0; kk < 2; ++kk) {
      #pragma unroll
      for (int m = 0; m < 2; ++m) {
        bf16x8 ap = *(const bf16x8*)(lpr + m * 1152 + kk * 32);
        o[m][0] = __builtin_amdgcn_mfma_f32_16x16x32_bf16(ap, bv[kk][0], o[m][0], 0, 0, 0);
        o[m][1] = __builtin_amdgcn_mfma_f32_16x16x32_bf16(ap, bv[kk][1], o[m][1], 0, 0, 0);
        o[m][2] = __builtin_amdgcn_mfma_f32_16x16x32_bf16(ap, bones, o[m][2], 0, 0, 0);
      }
    }

    if (kt + 1 < ntiles) {
      commit(swp);          // writes NEXT buffer: nobody reads it until the barrier
      __syncthreads();
    }
  }

  // epilogue: unnormalized O + per-head l packed into Opart rows
  #pragma unroll
  for (int m = 0; m < 2; ++m) {
    #pragma unroll
    for (int r = 0; r < 4; ++r) {
      int gq = q0 + m * 16 + quad * 4 + r;
      if (gq < NQ) {
        float* rowp = Opart + (size_t)split * OSPLIT_F + (size_t)gq * OROW_F;
        rowp[h * DHEAD + n16] = o[m][0][r];
        rowp[h * DHEAD + 16 + n16] = o[m][1][r];
        if (n16 == 0) rowp[128 + h] = o[m][2][r];
      }
    }
  }
}

// ============ merge + proj + preLN + MLP + postLN (MFMA), 16 q/block ============
__global__ __launch_bounds__(256) void mlp_kernel(
    const float* __restrict__ Opart, int ksplit,
    const float* __restrict__ skip,
    const __hip_bfloat16* __restrict__ wball,
    const float* __restrict__ bproj,
    const float* __restrict__ pre_g, const float* __restrict__ pre_b,
    const float* __restrict__ b1, const float* __restrict__ b2,
    const float* __restrict__ post_g, const float* __restrict__ post_b,
    float* __restrict__ out)
{
  __shared__ __hip_bfloat16 sab[16][136];
  __shared__ __hip_bfloat16 znb[16][136];
  __shared__ float znf[16][132];
  __shared__ __hip_bfloat16 hb[16][264];
  __shared__ float part[16][4][2];

  const __hip_bfloat16* wprojb = wball + WPROJB;
  const __hip_bfloat16* w1b    = wball + W1B;
  const __hip_bfloat16* w2b    = wball + W2B;

  const int t = threadIdx.x;
  const int q0 = blockIdx.x * TQ;

  // ---- merge k-splits (fixed softmax base: plain sums) ----
  {
    int row = t >> 4, c0 = (t & 15) * 8;
    int gq = q0 + row; int cq = gq < NQ ? gq : NQ - 1;
    int head = c0 >> 5;
    float ll = 0.f;
    float acc8[8] = {};
    for (int s = 0; s < ksplit; ++s) {
      const float* rp = Opart + (size_t)s * OSPLIT_F + (size_t)cq * OROW_F;
      ll += rp[128 + head];
      float4 a = *(const float4*)(rp + c0);
      float4 b = *(const float4*)(rp + c0 + 4);
      acc8[0] += a.x; acc8[1] += a.y; acc8[2] += a.z; acc8[3] += a.w;
      acc8[4] += b.x; acc8[5] += b.y; acc8[6] += b.z; acc8[7] += b.w;
    }
    float rll = 1.f / fmaxf(ll, 1e-30f);
    #pragma unroll
    for (int i = 0; i < 8; ++i)
      sab[row][c0 + i] = __float2bfloat16(acc8[i] * rll);
  }
  __syncthreads();

  const int wid = t >> 6, lane = t & 63;
  const int n16 = lane & 15, quad = lane >> 4;
  const int qrow0 = q0 + quad * 4;

  // ---- GEMM1: proj 128->128 ----
  f32x4 acc1[2] = {};
  for (int kt = 0; kt < 4; ++kt) {
    bf16x8 af = *(const bf16x8*)&sab[n16][kt * 32 + quad * 8];
    #pragma unroll
    for (int ni = 0; ni < 2; ++ni) {
      int o = wid * 32 + ni * 16 + n16;
      bf16x8 bw = *(const bf16x8*)(wprojb + (size_t)o * 128 + kt * 32 + quad * 8);
      acc1[ni] = __builtin_amdgcn_mfma_f32_16x16x32_bf16(af, bw, acc1[ni], 0, 0, 0);
    }
  }
  float z[2][4];
  #pragma unroll
  for (int ni = 0; ni < 2; ++ni) {
    int o = wid * 32 + ni * 16 + n16;
    float bo = bproj[o];
    if (qrow0 + 3 < NQ) {
      float4 sk = *(const float4*)(skip + (size_t)o * NQ + qrow0);
      z[ni][0] = acc1[ni][0] + bo + sk.x;
      z[ni][1] = acc1[ni][1] + bo + sk.y;
      z[ni][2] = acc1[ni][2] + bo + sk.z;
      z[ni][3] = acc1[ni][3] + bo + sk.w;
    } else {
      #pragma unroll
      for (int rg = 0; rg < 4; ++rg) {
        int cq = qrow0 + rg < NQ ? qrow0 + rg : NQ - 1;
        z[ni][rg] = acc1[ni][rg] + bo + skip[(size_t)o * NQ + cq];
      }
    }
  }
  #pragma unroll
  for (int rg = 0; rg < 4; ++rg) {
    float s = z[0][rg] + z[1][rg];
    float ss = z[0][rg] * z[0][rg] + z[1][rg] * z[1][rg];
    s += __shfl_xor(s, 1);  ss += __shfl_xor(ss, 1);
    s += __shfl_xor(s, 2);  ss += __shfl_xor(ss, 2);
    s += __shfl_xor(s, 4);  ss += __shfl_xor(ss, 4);
    s += __shfl_xor(s, 8);  ss += __shfl_xor(ss, 8);
    if (n16 == 0) { part[quad * 4 + rg][wid][0] = s; part[quad * 4 + rg][wid][1] = ss; }
  }
  __syncthreads();
  #pragma unroll
  for (int rg = 0; rg < 4; ++rg) {
    int row = quad * 4 + rg;
    float S  = part[row][0][0] + part[row][1][0] + part[row][2][0] + part[row][3][0];
    float SS = part[row][0][1] + part[row][1][1] + part[row][2][1] + part[row][3][1];
    float mean = S * (1.f / 128.f);
    float var  = SS * (1.f / 128.f) - mean * mean;
    float rstd = rsqrtf(fmaxf(var, 0.f) + 1e-5f);
    #pragma unroll
    for (int ni = 0; ni < 2; ++ni) {
      int o = wid * 32 + ni * 16 + n16;
      float zn = (z[ni][rg] - mean) * rstd * pre_g[o] + pre_b[o];
      znf[row][o] = zn;
      znb[row][o] = __float2bfloat16(zn);
    }
  }
  __syncthreads();

  // ---- GEMM2: 128 -> 256 + GELU ----
  f32x4 acc2[4] = {};
  for (int kt = 0; kt < 4; ++kt) {
    bf16x8 af = *(const bf16x8*)&znb[n16][kt * 32 + quad * 8];
    #pragma unroll
    for (int ni = 0; ni < 4; ++ni) {
      int j = wid * 64 + ni * 16 + n16;
      bf16x8 bw = *(const bf16x8*)(w1b + (size_t)j * 128 + kt * 32 + quad * 8);
      acc2[ni] = __builtin_amdgcn_mfma_f32_16x16x32_bf16(af, bw, acc2[ni], 0, 0, 0);
    }
  }
  #pragma unroll
  for (int ni = 0; ni < 4; ++ni) {
    int j = wid * 64 + ni * 16 + n16;
    float bj = b1[j];
    #pragma unroll
    for (int rg = 0; rg < 4; ++rg) {
      float a1 = acc2[ni][rg] + bj;
      hb[quad * 4 + rg][j] = __float2bfloat16(0.5f * a1 * (1.0f + erff(a1 * 0.70710678118654752f)));
    }
  }
  __syncthreads();

  // ---- GEMM3: 256 -> 128 + residual + postLN ----
  f32x4 acc3[2] = {};
  for (int kt = 0; kt < 8; ++kt) {
    bf16x8 af = *(const bf16x8*)&hb[n16][kt * 32 + quad * 8];
    #pragma unroll
    for (int ni = 0; ni < 2; ++ni) {
      int o = wid * 32 + ni * 16 + n16;
      bf16x8 bw = *(const bf16x8*)(w2b + (size_t)o * 256 + kt * 32 + quad * 8);
      acc3[ni] = __builtin_amdgcn_mfma_f32_16x16x32_bf16(af, bw, acc3[ni], 0, 0, 0);
    }
  }
  float y[2][4];
  #pragma unroll
  for (int ni = 0; ni < 2; ++ni) {
    int o = wid * 32 + ni * 16 + n16;
    float bo = b2[o];
    #pragma unroll
    for (int rg = 0; rg < 4; ++rg)
      y[ni][rg] = znf[quad * 4 + rg][o] + acc3[ni][rg] + bo;
  }
  #pragma unroll
  for (int rg = 0; rg < 4; ++rg) {
    float s = y[0][rg] + y[1][rg];
    float ss = y[0][rg] * y[0][rg] + y[1][rg] * y[1][rg];
    s += __shfl_xor(s, 1);  ss += __shfl_xor(ss, 1);
    s += __shfl_xor(s, 2);  ss += __shfl_xor(ss, 2);
    s += __shfl_xor(s, 4);  ss += __shfl_xor(ss, 4);
    s += __shfl_xor(s, 8);  ss += __shfl_xor(ss, 8);
    if (n16 == 0) { part[quad * 4 + rg][wid][0] = s; part[quad * 4 + rg][wid][1] = ss; }
  }
  __syncthreads();
  #pragma unroll
  for (int rg = 0; rg < 4; ++rg) {
    int row = quad * 4 + rg;
    float S  = part[row][0][0] + part[row][1][0] + part[row][2][0] + part[row][3][0];
    float SS = part[row][0][1] + part[row][1][1] + part[row][2][1] + part[row][3][1];
    float mean = S * (1.f / 128.f);
    float var  = SS * (1.f / 128.f) - mean * mean;
    float rstd = rsqrtf(fmaxf(var, 0.f) + 1e-5f);
    #pragma unroll
    for (int ni = 0; ni < 2; ++ni) {
      int o = wid * 32 + ni * 16 + n16;
      y[ni][rg] = (y[ni][rg] - mean) * rstd * post_g[o] + post_b[o];
    }
  }
  #pragma unroll
  for (int ni = 0; ni < 2; ++ni) {
    int o = wid * 32 + ni * 16 + n16;
    if (qrow0 + 3 < NQ) {
      *(float4*)(out + (size_t)o * NQ + qrow0) = make_float4(y[ni][0], y[ni][1], y[ni][2], y[ni][3]);
    } else {
      #pragma unroll
      for (int rg = 0; rg < 4; ++rg)
        if (qrow0 + rg < NQ) out[(size_t)o * NQ + qrow0 + rg] = y[ni][rg];
    }
  }
}

extern "C" void kernel_launch(void* const* d_in, const int* in_sizes, int n_in,
                              void* d_out, int out_size, void* d_ws, size_t ws_size,
                              hipStream_t stream) {
  if (ws_size < WS_REQ3) return;  // fail-safe (clean zero output)
  int ksplit = (int)((ws_size - WS_OP) / (size_t)(OSPLIT_F * 4));
  if (ksplit > 12) ksplit = 12;
  if (ksplit < 3)  ksplit = 3;

  const float* q     = (const float*)d_in[0];
  const float* k     = (const float*)d_in[1];
  const float* v     = (const float*)d_in[2];
  const float* Wl    = (const float*)d_in[3];
  const int*   vis   = (const int*)d_in[4];
  const float* skip  = (const float*)d_in[5];
  const float* qn_g  = (const float*)d_in[6];
  const float* qn_b  = (const float*)d_in[7];
  const float* kn_g  = (const float*)d_in[8];
  const float* kn_b  = (const float*)d_in[9];
  const float* vn_g  = (const float*)d_in[10];
  const float* vn_b  = (const float*)d_in[11];
  const float* wq    = (const float*)d_in[12];
  const float* bq    = (const float*)d_in[13];
  const float* wk    = (const float*)d_in[14];
  const float* bk    = (const float*)d_in[15];
  const float* wv    = (const float*)d_in[16];
  const float* bv    = (const float*)d_in[17];
  const float* wproj = (const float*)d_in[18];
  const float* bproj = (const float*)d_in[19];
  const float* pre_g = (const float*)d_in[20];
  const float* pre_b = (const float*)d_in[21];
  const float* w1    = (const float*)d_in[22];
  const float* b1    = (const float*)d_in[23];
  const float* w2    = (const float*)d_in[24];
  const float* b2    = (const float*)d_in[25];
  const float* post_g= (const float*)d_in[26];
  const float* post_b= (const float*)d_in[27];

  char* ws = (char*)d_ws;
  __hip_bfloat16* Qp = (__hip_bfloat16*)(ws + WS_QP);
  __hip_bfloat16* Kp = (__hip_bfloat16*)(ws + WS_KP);
  __hip_bfloat16* Vt = (__hip_bfloat16*)(ws + WS_VT);
  __hip_bfloat16* Wb = (__hip_bfloat16*)(ws + WS_WB);
  float* Opart = (float*)(ws + WS_OP);

  hipLaunchKernelGGL(wconv_kernel, dim3(128), dim3(256), 0, stream,
                     wq, wk, wv, wproj, w1, w2, Wb);

  hipLaunchKernelGGL(lnproj_kernel, dim3(475), dim3(256), 0, stream,
                     q, k, v, qn_g, qn_b, kn_g, kn_b, vn_g, vn_b,
                     Wb, bq, bk, bv, Qp, Kp, Vt);

  hipLaunchKernelGGL(attn_kernel, dim3(AQBLOCKS, ksplit), dim3(256), 0, stream,
                     Qp, Kp, Vt, Wl, vis, Opart);

  hipLaunchKernelGGL(mlp_kernel, dim3(QBLOCKS), dim3(256), 0, stream,
                     Opart, ksplit, skip, Wb, bproj, pre_g, pre_b,
                     b1, b2, post_g, post_b, (float*)d_out);
}